// Round 8
// baseline (828.498 us; speedup 1.0000x reference)
//
#include <hip/hip_runtime.h>
#include <cstddef>
#include <cstdint>

#define B_     8
#define N_     512
#define HID_   512
#define HEADS_ 16
#define HD_    32
#define FFN_   2048
#define DEMB_  64
#define ROWS   (B_*N_)   // 4096

typedef unsigned short u16;
typedef short bf16x8 __attribute__((ext_vector_type(8)));
typedef float f32x4  __attribute__((ext_vector_type(4)));
typedef short short8v __attribute__((ext_vector_type(8)));
typedef short short4v __attribute__((ext_vector_type(4)));

__device__ __forceinline__ u16 f2bf(float f) {   // RNE float->bf16
  unsigned u = __float_as_uint(f);
  u += 0x7fffu + ((u >> 16) & 1u);
  return (u16)(u >> 16);
}
__device__ __forceinline__ float bf2f(u16 b) {
  return __uint_as_float(((unsigned)b) << 16);
}

__device__ __forceinline__ void gload16(const void* g, void* l) {
  // async global->LDS, 16B/lane; LDS dest = wave-uniform base + lane*16
  __builtin_amdgcn_global_load_lds(
      (const __attribute__((address_space(1))) unsigned int*)g,
      (__attribute__((address_space(3))) unsigned int*)l, 16, 0, 0);
}

// ---------------- prep: 4x weight transpose-cast + mask dtype detect ----------------
__device__ __forceinline__ void wt_tile(const float* __restrict__ W,
                                        u16* __restrict__ Wt,
                                        int K, int N, int tt, int tid) {
  __shared__ float tile[32][33];
  const int nt = N / 32;
  const int n0 = (tt % nt) * 32, k0 = (tt / nt) * 32;
  const int tx = tid & 31, ty = tid >> 5;  // ty 0..7
  #pragma unroll
  for (int i = 0; i < 4; ++i)
    tile[ty + 8 * i][tx] = W[(size_t)(k0 + ty + 8 * i) * N + n0 + tx];
  __syncthreads();
  #pragma unroll
  for (int i = 0; i < 4; ++i) {
    const int n = ty + 8 * i;
    Wt[(size_t)(n0 + n) * K + k0 + tx] = f2bf(tile[tx][n]);
  }
}

__global__ __launch_bounds__(256) void prep_kernel(
    const float* __restrict__ qkv_w, const float* __restrict__ out_w,
    const float* __restrict__ ff1_w, const float* __restrict__ ff2_w,
    u16* __restrict__ qkv_wt, u16* __restrict__ out_wt,
    u16* __restrict__ ff1_wt, u16* __restrict__ ff2_wt,
    const unsigned char* __restrict__ mask, int* __restrict__ flag) {
  const int bid = blockIdx.x, t = threadIdx.x;
  if (bid < 768) {
    wt_tile(qkv_w, qkv_wt, HID_, 3 * HID_, bid, t);
  } else if (bid < 1024) {
    wt_tile(out_w, out_wt, HID_, HID_, bid - 768, t);
  } else if (bid < 2048) {
    wt_tile(ff1_w, ff1_wt, HID_, FFN_, bid - 1024, t);
  } else if (bid < 3072) {
    wt_tile(ff2_w, ff2_wt, FFN_, HID_, bid - 2048, t);
  } else {
    // mask dtype detect: numpy bool -> random bytes everywhere;
    // int32 0/1 -> bytes at offset%4 != 0 are always 0.
    const int idx = (bid - 3072) * 256 + t;   // 0..65535
    if ((idx & 3) != 0 && mask[idx] != 0) atomicOr(flag, 1);
  }
}

// ---------------- LayerNorm (fp32 in -> bf16 out): one wave per row ----------------
__global__ __launch_bounds__(256) void ln_kernel(const float* __restrict__ x,
                                                 const float* __restrict__ g,
                                                 const float* __restrict__ bt,
                                                 u16* __restrict__ y) {
  const int lane = threadIdx.x & 63;
  const int row  = blockIdx.x * 4 + (threadIdx.x >> 6);
  const float* xr = x + (size_t)row * HID_;
  float4 v0 = *(const float4*)(xr + lane * 8);
  float4 v1 = *(const float4*)(xr + lane * 8 + 4);
  float s = v0.x + v0.y + v0.z + v0.w + v1.x + v1.y + v1.z + v1.w;
  float q = v0.x*v0.x + v0.y*v0.y + v0.z*v0.z + v0.w*v0.w
          + v1.x*v1.x + v1.y*v1.y + v1.z*v1.z + v1.w*v1.w;
  #pragma unroll
  for (int off = 32; off > 0; off >>= 1) {
    s += __shfl_xor(s, off, 64);
    q += __shfl_xor(q, off, 64);
  }
  const float mean = s * (1.0f / HID_);
  const float var  = q * (1.0f / HID_) - mean * mean;
  const float rs   = rsqrtf(var + 1e-5f);
  const float4 g0 = *(const float4*)(g + lane * 8);
  const float4 g1 = *(const float4*)(g + lane * 8 + 4);
  const float4 b0 = *(const float4*)(bt + lane * 8);
  const float4 b1 = *(const float4*)(bt + lane * 8 + 4);
  short8v o;
  o[0] = (short)f2bf((v0.x - mean) * rs * g0.x + b0.x);
  o[1] = (short)f2bf((v0.y - mean) * rs * g0.y + b0.y);
  o[2] = (short)f2bf((v0.z - mean) * rs * g0.z + b0.z);
  o[3] = (short)f2bf((v0.w - mean) * rs * g0.w + b0.w);
  o[4] = (short)f2bf((v1.x - mean) * rs * g1.x + b1.x);
  o[5] = (short)f2bf((v1.y - mean) * rs * g1.y + b1.y);
  o[6] = (short)f2bf((v1.z - mean) * rs * g1.z + b1.z);
  o[7] = (short)f2bf((v1.w - mean) * rs * g1.w + b1.w);
  *(short8v*)(y + (size_t)row * HID_ + lane * 8) = o;
}

// ---------------- bf16 MFMA GEMM (single-buffer, r6 schedule) ----------------
// A[M][K] bf16 row-major; Wt[N][K] bf16. 128x128 tile, BK=64, 4 waves,
// mfma_f32_16x16x32_bf16, fp32 accum. 32 KB LDS -> higher occupancy
// (the 64 KB double-buffer variant regressed, m132-class).
// XOR swizzle (slot ^= row&7) on global source + ds_read (rule #21).
template <int ACT, bool HAS_RES, bool OUT_BF16>
__global__ __launch_bounds__(256) void mfma_gemm(
    const u16* __restrict__ A, const u16* __restrict__ Wt,
    const float* __restrict__ bias, const float* __restrict__ res,
    void* __restrict__ Cout, int N, int K) {
  __shared__ __align__(16) u16 As[128 * 64];
  __shared__ __align__(16) u16 Bs[128 * 64];
  const int t    = threadIdx.x;
  const int wid  = t >> 6, lane = t & 63;
  const int wr   = wid >> 1, wc = wid & 1;      // wave -> 64x64 quadrant
  const int m0   = blockIdx.y * 128, n0 = blockIdx.x * 128;
  const int srow8 = lane >> 3;                  // 0..7
  const int sslot = (lane & 7) ^ srow8;         // inverse-swizzled k-slot

  f32x4 zero = {0.f, 0.f, 0.f, 0.f};
  f32x4 acc[4][4];
  #pragma unroll
  for (int m = 0; m < 4; ++m)
    #pragma unroll
    for (int n = 0; n < 4; ++n) acc[m][n] = zero;

  for (int kt = 0; kt < K; kt += 64) {
    __syncthreads();   // previous compute done before overwriting LDS
    #pragma unroll
    for (int i = 0; i < 4; ++i) {
      const int rbase = wid * 32 + i * 8;
      const int r = rbase + srow8;
      gload16(A  + (size_t)(m0 + r) * K + kt + sslot * 8, &As[rbase * 64]);
      gload16(Wt + (size_t)(n0 + r) * K + kt + sslot * 8, &Bs[rbase * 64]);
    }
    __syncthreads();   // drains vmcnt(0) before barrier
    #pragma unroll
    for (int kk = 0; kk < 2; ++kk) {
      bf16x8 a[4], b[4];
      #pragma unroll
      for (int m = 0; m < 4; ++m) {
        const int row = wr * 64 + m * 16 + (lane & 15);
        const int s   = (kk * 4 + (lane >> 4)) ^ (row & 7);
        a[m] = *(const bf16x8*)&As[row * 64 + s * 8];
      }
      #pragma unroll
      for (int n = 0; n < 4; ++n) {
        const int row = wc * 64 + n * 16 + (lane & 15);
        const int s   = (kk * 4 + (lane >> 4)) ^ (row & 7);
        b[n] = *(const bf16x8*)&Bs[row * 64 + s * 8];
      }
      #pragma unroll
      for (int m = 0; m < 4; ++m)
        #pragma unroll
        for (int n = 0; n < 4; ++n)
          acc[m][n] = __builtin_amdgcn_mfma_f32_16x16x32_bf16(
              a[m], b[n], acc[m][n], 0, 0, 0);
    }
  }
  // epilogue: C/D layout col=lane&15, row=(lane>>4)*4+reg (m89-verified)
  #pragma unroll
  for (int n = 0; n < 4; ++n) {
    const int col = n0 + wc * 64 + n * 16 + (lane & 15);
    const float bb = bias[col];
    #pragma unroll
    for (int m = 0; m < 4; ++m) {
      #pragma unroll
      for (int j = 0; j < 4; ++j) {
        const int row = m0 + wr * 64 + m * 16 + (lane >> 4) * 4 + j;
        float v = acc[m][n][j] + bb;
        if (ACT == 1) v = 0.5f * v * (1.0f + erff(v * 0.70710678118654752f));
        const size_t off = (size_t)row * N + col;
        if (HAS_RES) v += res[off];
        if (OUT_BF16) ((u16*)Cout)[off] = f2bf(v);
        else          ((float*)Cout)[off] = v;
      }
    }
  }
}

// ---------------- fused distance-bias + mask (v4: MFMA) ----------------
__global__ __launch_bounds__(256) void bias_kernel(
    const float* __restrict__ df, const unsigned char* __restrict__ mask8,
    const float* __restrict__ dw, const float* __restrict__ db,
    const int* __restrict__ flag, u16* __restrict__ biasb) {
  __shared__ __align__(16) float dfs[128 * 64];   // 32 KB, group-swizzled
  __shared__ float wls[64 * 16];                  // 4 KB, [d][h] linear
  __shared__ float dbs[16];
  __shared__ unsigned char mbuf[128];
  __shared__ u16 obuf[16][132];                   // pad 132 -> conflict-free

  const int t    = threadIdx.x;
  const int wid  = t >> 6, lane = t & 63;
  const int tile = blockIdx.x & 3;
  const int i    = (blockIdx.x >> 2) & 511;
  const int b    = blockIdx.x >> 11;
  const int j0   = tile * 128;

  // stage df[128 rows][64 f32]: physical 16B-slot p of row r holds group p^(r&15)
  const size_t dfbase = (((size_t)b * N_ + i) * N_ + j0) * DEMB_;
  #pragma unroll
  for (int s = 0; s < 8; ++s) {
    const int r0 = wid * 32 + s * 4;
    const int r  = r0 + (lane >> 4);
    const int g  = (lane & 15) ^ (r & 15);
    gload16(df + dfbase + (size_t)r * DEMB_ + g * 4, &dfs[r0 * 64]);
  }
  // stage dist_w (f32 [64][16], 4KB, linear) + db + decoded mask
  *(float4*)&wls[t * 4] = ((const float4*)dw)[t];
  if (t < 16) dbs[t] = db[t];
  const int fb = *flag;
  if (t < 128) {
    const size_t midx = ((size_t)b * N_ + i) * N_ + j0 + t;
    mbuf[t] = fb ? (mask8[midx] != 0) : (((const int*)mask8)[midx] != 0);
  }
  __syncthreads();

  // B frags: lane holds col h=lane&15, k = kk*32 + (lane>>4)*8 + e
  bf16x8 bw[2];
  #pragma unroll
  for (int kk = 0; kk < 2; ++kk)
    #pragma unroll
    for (int e = 0; e < 8; ++e) {
      const int k = kk * 32 + (lane >> 4) * 8 + e;
      bw[kk][e] = (short)f2bf(wls[k * 16 + (lane & 15)]);
    }

  // A frags + MFMA: wave -> rows [wid*32, wid*32+32) as 2 tiles of 16
  f32x4 acc[2] = {{0.f,0.f,0.f,0.f},{0.f,0.f,0.f,0.f}};
  #pragma unroll
  for (int t8 = 0; t8 < 2; ++t8) {
    const int row = wid * 32 + t8 * 16 + (lane & 15);
    #pragma unroll
    for (int kk = 0; kk < 2; ++kk) {
      bf16x8 a;
      #pragma unroll
      for (int gg = 0; gg < 2; ++gg) {
        const int G = kk * 8 + (lane >> 4) * 2 + gg;
        const int p = G ^ (row & 15);
        const float4 v = *(const float4*)&dfs[row * 64 + p * 4];
        a[gg*4+0] = (short)f2bf(v.x); a[gg*4+1] = (short)f2bf(v.y);
        a[gg*4+2] = (short)f2bf(v.z); a[gg*4+3] = (short)f2bf(v.w);
      }
      acc[t8] = __builtin_amdgcn_mfma_f32_16x16x32_bf16(a, bw[kk], acc[t8], 0, 0, 0);
    }
  }

  // epilogue: C col=lane&15 (h), row=(lane>>4)*4+j -> obuf, then coalesced out
  const int h = lane & 15;
  #pragma unroll
  for (int t8 = 0; t8 < 2; ++t8)
    #pragma unroll
    for (int j = 0; j < 4; ++j) {
      const int jl = wid * 32 + t8 * 16 + (lane >> 4) * 4 + j;
      const float v = acc[t8][j] + dbs[h];
      obuf[h][jl] = f2bf(mbuf[jl] ? v : -1e30f);
    }
  __syncthreads();
  const int h2 = t >> 4, c = t & 15;
  u16* ob = biasb + (((size_t)b * HEADS_ + h2) * N_ + i) * N_ + j0;
  *(short8v*)(ob + c * 8) = *(const short8v*)&obuf[h2][c * 8];
}

// ---------------- flash attention v3 ----------------
// grid = (b, h, iblk of 64 rows) = 1024 blocks; 256 thr = 4 waves.
// Wave jq handles j in [jq*128, jq*128+128) for all 64 rows (lane = row).
__global__ __launch_bounds__(256) void attn_kernel(
    const float* __restrict__ qkv, const u16* __restrict__ biasb,
    u16* __restrict__ ctx) {
  __shared__ union {
    u16 k[N_ * HD_];               // 32 KB  Ks[j][d]
    struct {
      float po[3][64][33];         // +1 pad -> conflict-free combine
      float pm[3][64];
      float pl[3][64];
    } c;
  } sm;
  const int t    = threadIdx.x;
  const int bx   = blockIdx.x;
  const int b    = bx >> 7;
  const int h    = (bx >> 3) & 15;
  const int iblk = bx & 7;
  const int jq   = t >> 6;         // wave id = j-quarter
  const int r    = t & 63;         // lane = row within block
  const int i    = iblk * 64 + r;
  const size_t qbase = (size_t)b * N_ * (3 * HID_);

  for (int idx = t; idx < N_ * 8; idx += 256) {
    const int j = idx >> 3, f = idx & 7;
    const float4 kv = *(const float4*)(qkv + qbase + (size_t)j * (3 * HID_) +
                                       HID_ + h * HD_ + f * 4);
    short4v ks;
    ks[0] = (short)f2bf(kv.x); ks[1] = (short)f2bf(kv.y);
    ks[2] = (short)f2bf(kv.z); ks[3] = (short)f2bf(kv.w);
    *(short4v*)&sm.k[j * HD_ + f * 4] = ks;
  }
  __syncthreads();

  float q[HD_];
  {
    const float* qp = qkv + qbase + (size_t)i * (3 * HID_) + h * HD_;
    #pragma unroll
    for (int f = 0; f < 8; ++f) {
      const float4 v = *(const float4*)(qp + f * 4);
      q[f*4+0] = v.x * 0.17677669529663687f;
      q[f*4+1] = v.y * 0.17677669529663687f;
      q[f*4+2] = v.z * 0.17677669529663687f;
      q[f*4+3] = v.w * 0.17677669529663687f;
    }
  }
  const u16* brow = biasb + (((size_t)b * HEADS_ + h) * N_ + i) * N_ + jq * 128;
  const float* vbase = qkv + qbase + 2 * HID_ + h * HD_;
  float m = -3.0e38f, l = 0.f;
  float o[HD_];
  #pragma unroll
  for (int d = 0; d < HD_; ++d) o[d] = 0.f;

  for (int j8 = 0; j8 < 128; j8 += 8) {
    const short8v bq = *(const short8v*)(brow + j8);
    #pragma unroll
    for (int e = 0; e < 8; ++e) {
      const int j = jq * 128 + j8 + e;
      const u16* kr = &sm.k[j * HD_];
      float s = 0.f;
      #pragma unroll
      for (int c = 0; c < 4; ++c) {
        const short8v kk = *(const short8v*)(kr + c * 8);
        #pragma unroll
        for (int d = 0; d < 8; ++d)
          s += q[c*8+d] * bf2f((u16)kk[d]);
      }
      s += bf2f((u16)bq[e]);
      if (s - m > 8.0f) {                  // defer-max (T13)
        const float corr = __expf(m - s);
        l *= corr;
        #pragma unroll
        for (int d = 0; d < HD_; ++d) o[d] *= corr;
        m = s;
      }
      const float p = __expf(s - m);
      l += p;
      const float4* vr = (const float4*)(vbase + (size_t)j * (3 * HID_));
      #pragma unroll
      for (int c = 0; c < 8; ++c) {
        const float4 vv = vr[c];
        o[c*4+0] += p * vv.x; o[c*4+1] += p * vv.y;
        o[c*4+2] += p * vv.z; o[c*4+3] += p * vv.w;
      }
    }
  }

  __syncthreads();                  // Ks dead; LDS reused for combine
  if (jq > 0) {
    sm.c.pm[jq-1][r] = m;
    sm.c.pl[jq-1][r] = l;
    #pragma unroll
    for (int d = 0; d < HD_; ++d) sm.c.po[jq-1][r][d] = o[d];
  }
  __syncthreads();
  if (jq == 0) {
    #pragma unroll
    for (int p2 = 0; p2 < 3; ++p2) {
      const float m2 = sm.c.pm[p2][r], l2 = sm.c.pl[p2][r];
      const float mn = fmaxf(m, m2);
      const float c1 = __expf(m - mn), c2 = __expf(m2 - mn);
      l = l * c1 + l2 * c2;
      #pragma unroll
      for (int d = 0; d < HD_; ++d)
        o[d] = o[d] * c1 + sm.c.po[p2][r][d] * c2;
      m = mn;
    }
    const float inv = 1.0f / l;
    u16* cp = ctx + (((size_t)b * N_ + i) * HEADS_ + h) * HD_;
    #pragma unroll
    for (int f = 0; f < 4; ++f) {
      short8v v;
      #pragma unroll
      for (int e = 0; e < 8; ++e) v[e] = (short)f2bf(o[f*8+e] * inv);
      *(short8v*)(cp + f * 8) = v;
    }
  }
}

// ---------------- launcher ----------------
extern "C" void kernel_launch(void* const* d_in, const int* in_sizes, int n_in,
                              void* d_out, int out_size, void* d_ws, size_t ws_size,
                              hipStream_t stream) {
  const float* x      = (const float*)d_in[0];
  const float* df     = (const float*)d_in[1];
  const unsigned char* mask = (const unsigned char*)d_in[2];
  const float* qkv_w  = (const float*)d_in[3];
  const float* qkv_b  = (const float*)d_in[4];
  const float* out_w  = (const float*)d_in[5];
  const float* out_b  = (const float*)d_in[6];
  const float* dist_w = (const float*)d_in[7];
  const float* dist_b = (const float*)d_in[8];
  const float* ln1_g  = (const float*)d_in[9];
  const float* ln1_b  = (const float*)d_in[10];
  const float* ln2_g  = (const float*)d_in[11];
  const float* ln2_b  = (const float*)d_in[12];
  const float* ff1_w  = (const float*)d_in[13];
  const float* ff1_b  = (const float*)d_in[14];
  const float* ff2_w  = (const float*)d_in[15];
  const float* ff2_b  = (const float*)d_in[16];
  float* out = (float*)d_out;

  char* p = (char*)d_ws;
  auto alloc = [&](size_t bytes) {
    char* r = p;
    p += (bytes + 255) & ~(size_t)255;
    return r;
  };
  float* qkv    = (float*)alloc((size_t)ROWS * 3 * HID_ * 4);
  u16*   biasb  = (u16*)alloc((size_t)B_ * HEADS_ * N_ * N_ * 2);
  float* xa     = (float*)alloc((size_t)ROWS * HID_ * 4);
  u16*   h16    = (u16*)alloc((size_t)ROWS * HID_ * 2);
  u16*   ctx16  = (u16*)alloc((size_t)ROWS * HID_ * 2);
  u16*   y16    = (u16*)alloc((size_t)ROWS * HID_ * 2);
  u16*   ff116  = (u16*)alloc((size_t)ROWS * FFN_ * 2);
  u16*   qkv_wt = (u16*)alloc((size_t)3 * HID_ * HID_ * 2);
  u16*   out_wt = (u16*)alloc((size_t)HID_ * HID_ * 2);
  u16*   ff1_wt = (u16*)alloc((size_t)FFN_ * HID_ * 2);
  u16*   ff2_wt = (u16*)alloc((size_t)HID_ * FFN_ * 2);
  int*   flag   = (int*)alloc(sizeof(int));

  hipMemsetAsync(flag, 0, sizeof(int), stream);
  prep_kernel<<<3328, 256, 0, stream>>>(qkv_w, out_w, ff1_w, ff2_w,
                                        qkv_wt, out_wt, ff1_wt, ff2_wt,
                                        mask, flag);
  // h16 = bf16(LN1(x))
  ln_kernel<<<ROWS / 4, 256, 0, stream>>>(x, ln1_g, ln1_b, h16);
  // qkv = h @ qkv_w + qkv_b   (f32 out)
  mfma_gemm<0, false, false><<<dim3(3 * HID_ / 128, ROWS / 128), 256, 0, stream>>>(
      h16, qkv_wt, qkv_b, nullptr, qkv, 3 * HID_, HID_);
  // biasb = bf16 masked distance bias [B,H,N,N]  (MFMA)
  bias_kernel<<<B_ * N_ * 4, 256, 0, stream>>>(df, mask, dist_w, dist_b, flag, biasb);
  // ctx16 = bf16(softmax(QK^T/sqrt(hd) + biasb) @ V)
  // PROBE: launched 3x (idempotent) -> dur_us gains exactly 2*t_attn for
  // attribution; remove next round once t_attn is known.
  attn_kernel<<<B_ * HEADS_ * 8, 256, 0, stream>>>(qkv, biasb, ctx16);
  attn_kernel<<<B_ * HEADS_ * 8, 256, 0, stream>>>(qkv, biasb, ctx16);
  attn_kernel<<<B_ * HEADS_ * 8, 256, 0, stream>>>(qkv, biasb, ctx16);
  // xa = x + ctx @ out_w + out_b   (f32 out)
  mfma_gemm<0, true, false><<<dim3(HID_ / 128, ROWS / 128), 256, 0, stream>>>(
      ctx16, out_wt, out_b, x, xa, HID_, HID_);
  // y16 = bf16(LN2(xa))
  ln_kernel<<<ROWS / 4, 256, 0, stream>>>(xa, ln2_g, ln2_b, y16);
  // ff116 = bf16(gelu(y @ ff1_w + ff1_b))
  mfma_gemm<1, false, true><<<dim3(FFN_ / 128, ROWS / 128), 256, 0, stream>>>(
      y16, ff1_wt, ff1_b, nullptr, ff116, FFN_, HID_);
  // out = xa + ff1 @ ff2_w + ff2_b   (f32 out)
  mfma_gemm<0, true, false><<<dim3(HID_ / 128, ROWS / 128), 256, 0, stream>>>(
      ff116, ff2_wt, ff2_b, xa, out, HID_, FFN_);
}

// Round 9
// 435.757 us; speedup vs baseline: 1.9013x; 1.9013x over previous
//
#include <hip/hip_runtime.h>
#include <cstddef>
#include <cstdint>

#define B_     8
#define N_     512
#define HID_   512
#define HEADS_ 16
#define HD_    32
#define FFN_   2048
#define DEMB_  64
#define ROWS   (B_*N_)   // 4096

typedef unsigned short u16;
typedef short bf16x8 __attribute__((ext_vector_type(8)));
typedef float f32x4  __attribute__((ext_vector_type(4)));
typedef short short8v __attribute__((ext_vector_type(8)));
typedef short short4v __attribute__((ext_vector_type(4)));

__device__ __forceinline__ u16 f2bf(float f) {   // RNE float->bf16
  unsigned u = __float_as_uint(f);
  u += 0x7fffu + ((u >> 16) & 1u);
  return (u16)(u >> 16);
}
__device__ __forceinline__ float bf2f(u16 b) {
  return __uint_as_float(((unsigned)b) << 16);
}

__device__ __forceinline__ void gload16(const void* g, void* l) {
  // async global->LDS, 16B/lane; LDS dest = wave-uniform base + lane*16
  __builtin_amdgcn_global_load_lds(
      (const __attribute__((address_space(1))) unsigned int*)g,
      (__attribute__((address_space(3))) unsigned int*)l, 16, 0, 0);
}

// ---------------- prep: 4x weight transpose-cast + mask dtype detect ----------------
__device__ __forceinline__ void wt_tile(const float* __restrict__ W,
                                        u16* __restrict__ Wt,
                                        int K, int N, int tt, int tid) {
  __shared__ float tile[32][33];
  const int nt = N / 32;
  const int n0 = (tt % nt) * 32, k0 = (tt / nt) * 32;
  const int tx = tid & 31, ty = tid >> 5;  // ty 0..7
  #pragma unroll
  for (int i = 0; i < 4; ++i)
    tile[ty + 8 * i][tx] = W[(size_t)(k0 + ty + 8 * i) * N + n0 + tx];
  __syncthreads();
  #pragma unroll
  for (int i = 0; i < 4; ++i) {
    const int n = ty + 8 * i;
    Wt[(size_t)(n0 + n) * K + k0 + tx] = f2bf(tile[tx][n]);
  }
}

__global__ __launch_bounds__(256) void prep_kernel(
    const float* __restrict__ qkv_w, const float* __restrict__ out_w,
    const float* __restrict__ ff1_w, const float* __restrict__ ff2_w,
    u16* __restrict__ qkv_wt, u16* __restrict__ out_wt,
    u16* __restrict__ ff1_wt, u16* __restrict__ ff2_wt,
    const unsigned char* __restrict__ mask, int* __restrict__ flag) {
  const int bid = blockIdx.x, t = threadIdx.x;
  if (bid < 768) {
    wt_tile(qkv_w, qkv_wt, HID_, 3 * HID_, bid, t);
  } else if (bid < 1024) {
    wt_tile(out_w, out_wt, HID_, HID_, bid - 768, t);
  } else if (bid < 2048) {
    wt_tile(ff1_w, ff1_wt, HID_, FFN_, bid - 1024, t);
  } else if (bid < 3072) {
    wt_tile(ff2_w, ff2_wt, FFN_, HID_, bid - 2048, t);
  } else {
    // mask dtype detect: numpy bool -> random bytes everywhere;
    // int32 0/1 -> bytes at offset%4 != 0 are always 0.
    const int idx = (bid - 3072) * 256 + t;   // 0..65535
    if ((idx & 3) != 0 && mask[idx] != 0) atomicOr(flag, 1);
  }
}

// ---------------- LayerNorm (fp32 in -> bf16 out): one wave per row ----------------
__global__ __launch_bounds__(256) void ln_kernel(const float* __restrict__ x,
                                                 const float* __restrict__ g,
                                                 const float* __restrict__ bt,
                                                 u16* __restrict__ y) {
  const int lane = threadIdx.x & 63;
  const int row  = blockIdx.x * 4 + (threadIdx.x >> 6);
  const float* xr = x + (size_t)row * HID_;
  float4 v0 = *(const float4*)(xr + lane * 8);
  float4 v1 = *(const float4*)(xr + lane * 8 + 4);
  float s = v0.x + v0.y + v0.z + v0.w + v1.x + v1.y + v1.z + v1.w;
  float q = v0.x*v0.x + v0.y*v0.y + v0.z*v0.z + v0.w*v0.w
          + v1.x*v1.x + v1.y*v1.y + v1.z*v1.z + v1.w*v1.w;
  #pragma unroll
  for (int off = 32; off > 0; off >>= 1) {
    s += __shfl_xor(s, off, 64);
    q += __shfl_xor(q, off, 64);
  }
  const float mean = s * (1.0f / HID_);
  const float var  = q * (1.0f / HID_) - mean * mean;
  const float rs   = rsqrtf(var + 1e-5f);
  const float4 g0 = *(const float4*)(g + lane * 8);
  const float4 g1 = *(const float4*)(g + lane * 8 + 4);
  const float4 b0 = *(const float4*)(bt + lane * 8);
  const float4 b1 = *(const float4*)(bt + lane * 8 + 4);
  short8v o;
  o[0] = (short)f2bf((v0.x - mean) * rs * g0.x + b0.x);
  o[1] = (short)f2bf((v0.y - mean) * rs * g0.y + b0.y);
  o[2] = (short)f2bf((v0.z - mean) * rs * g0.z + b0.z);
  o[3] = (short)f2bf((v0.w - mean) * rs * g0.w + b0.w);
  o[4] = (short)f2bf((v1.x - mean) * rs * g1.x + b1.x);
  o[5] = (short)f2bf((v1.y - mean) * rs * g1.y + b1.y);
  o[6] = (short)f2bf((v1.z - mean) * rs * g1.z + b1.z);
  o[7] = (short)f2bf((v1.w - mean) * rs * g1.w + b1.w);
  *(short8v*)(y + (size_t)row * HID_ + lane * 8) = o;
}

// ---------------- bf16 MFMA GEMM (single-buffer) ----------------
// A[M][K] bf16 row-major; Wt[N][K] bf16. 128x128 tile, BK=64, 4 waves,
// mfma_f32_16x16x32_bf16, fp32 accum. 32 KB LDS (dbuf regressed, m132-class).
// XOR swizzle (slot ^= row&7) on global source + ds_read (rule #21).
template <int ACT, bool HAS_RES, bool OUT_BF16>
__global__ __launch_bounds__(256) void mfma_gemm(
    const u16* __restrict__ A, const u16* __restrict__ Wt,
    const float* __restrict__ bias, const float* __restrict__ res,
    void* __restrict__ Cout, int N, int K) {
  __shared__ __align__(16) u16 As[128 * 64];
  __shared__ __align__(16) u16 Bs[128 * 64];
  const int t    = threadIdx.x;
  const int wid  = t >> 6, lane = t & 63;
  const int wr   = wid >> 1, wc = wid & 1;      // wave -> 64x64 quadrant
  const int m0   = blockIdx.y * 128, n0 = blockIdx.x * 128;
  const int srow8 = lane >> 3;                  // 0..7
  const int sslot = (lane & 7) ^ srow8;         // inverse-swizzled k-slot

  f32x4 zero = {0.f, 0.f, 0.f, 0.f};
  f32x4 acc[4][4];
  #pragma unroll
  for (int m = 0; m < 4; ++m)
    #pragma unroll
    for (int n = 0; n < 4; ++n) acc[m][n] = zero;

  for (int kt = 0; kt < K; kt += 64) {
    __syncthreads();   // previous compute done before overwriting LDS
    #pragma unroll
    for (int i = 0; i < 4; ++i) {
      const int rbase = wid * 32 + i * 8;
      const int r = rbase + srow8;
      gload16(A  + (size_t)(m0 + r) * K + kt + sslot * 8, &As[rbase * 64]);
      gload16(Wt + (size_t)(n0 + r) * K + kt + sslot * 8, &Bs[rbase * 64]);
    }
    __syncthreads();   // drains vmcnt(0) before barrier
    #pragma unroll
    for (int kk = 0; kk < 2; ++kk) {
      bf16x8 a[4], b[4];
      #pragma unroll
      for (int m = 0; m < 4; ++m) {
        const int row = wr * 64 + m * 16 + (lane & 15);
        const int s   = (kk * 4 + (lane >> 4)) ^ (row & 7);
        a[m] = *(const bf16x8*)&As[row * 64 + s * 8];
      }
      #pragma unroll
      for (int n = 0; n < 4; ++n) {
        const int row = wc * 64 + n * 16 + (lane & 15);
        const int s   = (kk * 4 + (lane >> 4)) ^ (row & 7);
        b[n] = *(const bf16x8*)&Bs[row * 64 + s * 8];
      }
      #pragma unroll
      for (int m = 0; m < 4; ++m)
        #pragma unroll
        for (int n = 0; n < 4; ++n)
          acc[m][n] = __builtin_amdgcn_mfma_f32_16x16x32_bf16(
              a[m], b[n], acc[m][n], 0, 0, 0);
    }
  }
  // epilogue: C/D layout col=lane&15, row=(lane>>4)*4+reg (m89-verified)
  #pragma unroll
  for (int n = 0; n < 4; ++n) {
    const int col = n0 + wc * 64 + n * 16 + (lane & 15);
    const float bb = bias[col];
    #pragma unroll
    for (int m = 0; m < 4; ++m) {
      #pragma unroll
      for (int j = 0; j < 4; ++j) {
        const int row = m0 + wr * 64 + m * 16 + (lane >> 4) * 4 + j;
        float v = acc[m][n][j] + bb;
        if (ACT == 1) v = 0.5f * v * (1.0f + erff(v * 0.70710678118654752f));
        const size_t off = (size_t)row * N + col;
        if (HAS_RES) v += res[off];
        if (OUT_BF16) ((u16*)Cout)[off] = f2bf(v);
        else          ((float*)Cout)[off] = v;
      }
    }
  }
}

// ---------------- fused distance-bias + mask (v4: MFMA) ----------------
__global__ __launch_bounds__(256) void bias_kernel(
    const float* __restrict__ df, const unsigned char* __restrict__ mask8,
    const float* __restrict__ dw, const float* __restrict__ db,
    const int* __restrict__ flag, u16* __restrict__ biasb) {
  __shared__ __align__(16) float dfs[128 * 64];   // 32 KB, group-swizzled
  __shared__ float wls[64 * 16];                  // 4 KB, [d][h] linear
  __shared__ float dbs[16];
  __shared__ unsigned char mbuf[128];
  __shared__ u16 obuf[16][132];                   // pad 132 -> conflict-free

  const int t    = threadIdx.x;
  const int wid  = t >> 6, lane = t & 63;
  const int tile = blockIdx.x & 3;
  const int i    = (blockIdx.x >> 2) & 511;
  const int b    = blockIdx.x >> 11;
  const int j0   = tile * 128;

  // stage df[128 rows][64 f32]: physical 16B-slot p of row r holds group p^(r&15)
  const size_t dfbase = (((size_t)b * N_ + i) * N_ + j0) * DEMB_;
  #pragma unroll
  for (int s = 0; s < 8; ++s) {
    const int r0 = wid * 32 + s * 4;
    const int r  = r0 + (lane >> 4);
    const int g  = (lane & 15) ^ (r & 15);
    gload16(df + dfbase + (size_t)r * DEMB_ + g * 4, &dfs[r0 * 64]);
  }
  // stage dist_w (f32 [64][16], 4KB, linear) + db + decoded mask
  *(float4*)&wls[t * 4] = ((const float4*)dw)[t];
  if (t < 16) dbs[t] = db[t];
  const int fb = *flag;
  if (t < 128) {
    const size_t midx = ((size_t)b * N_ + i) * N_ + j0 + t;
    mbuf[t] = fb ? (mask8[midx] != 0) : (((const int*)mask8)[midx] != 0);
  }
  __syncthreads();

  // B frags: lane holds col h=lane&15, k = kk*32 + (lane>>4)*8 + e
  bf16x8 bw[2];
  #pragma unroll
  for (int kk = 0; kk < 2; ++kk)
    #pragma unroll
    for (int e = 0; e < 8; ++e) {
      const int k = kk * 32 + (lane >> 4) * 8 + e;
      bw[kk][e] = (short)f2bf(wls[k * 16 + (lane & 15)]);
    }

  // A frags + MFMA: wave -> rows [wid*32, wid*32+32) as 2 tiles of 16
  f32x4 acc[2] = {{0.f,0.f,0.f,0.f},{0.f,0.f,0.f,0.f}};
  #pragma unroll
  for (int t8 = 0; t8 < 2; ++t8) {
    const int row = wid * 32 + t8 * 16 + (lane & 15);
    #pragma unroll
    for (int kk = 0; kk < 2; ++kk) {
      bf16x8 a;
      #pragma unroll
      for (int gg = 0; gg < 2; ++gg) {
        const int G = kk * 8 + (lane >> 4) * 2 + gg;
        const int p = G ^ (row & 15);
        const float4 v = *(const float4*)&dfs[row * 64 + p * 4];
        a[gg*4+0] = (short)f2bf(v.x); a[gg*4+1] = (short)f2bf(v.y);
        a[gg*4+2] = (short)f2bf(v.z); a[gg*4+3] = (short)f2bf(v.w);
      }
      acc[t8] = __builtin_amdgcn_mfma_f32_16x16x32_bf16(a, bw[kk], acc[t8], 0, 0, 0);
    }
  }

  // epilogue: C col=lane&15 (h), row=(lane>>4)*4+j -> obuf, then coalesced out
  const int h = lane & 15;
  #pragma unroll
  for (int t8 = 0; t8 < 2; ++t8)
    #pragma unroll
    for (int j = 0; j < 4; ++j) {
      const int jl = wid * 32 + t8 * 16 + (lane >> 4) * 4 + j;
      const float v = acc[t8][j] + dbs[h];
      obuf[h][jl] = f2bf(mbuf[jl] ? v : -1e30f);
    }
  __syncthreads();
  const int h2 = t >> 4, c = t & 15;
  u16* ob = biasb + (((size_t)b * HEADS_ + h2) * N_ + i) * N_ + j0;
  *(short8v*)(ob + c * 8) = *(const short8v*)&obuf[h2][c * 8];
}

// ---------------- flash attention v4: 16-j chunked inner loop ----------------
// grid = (b, h, iblk of 64 rows) = 1024 blocks; 256 thr = 4 waves.
// Wave jq handles j in [jq*128, jq*128+128) for all 64 rows (lane = row).
// v4: phases per 16-j chunk — (1) 16 independent QK dots (deep ILP),
// (2) chunk max -> ONE defer-max branch per 16 j, (3) 16 independent exp +
// tree-sum l, (4) PV with all p ready -> V loads pipeline with no dependency.
__global__ __launch_bounds__(256) void attn_kernel(
    const float* __restrict__ qkv, const u16* __restrict__ biasb,
    u16* __restrict__ ctx) {
  __shared__ union {
    u16 k[N_ * HD_];               // 32 KB  Ks[j][d]
    struct {
      float po[3][64][33];         // +1 pad -> conflict-free combine
      float pm[3][64];
      float pl[3][64];
    } c;
  } sm;
  const int t    = threadIdx.x;
  const int bx   = blockIdx.x;
  const int b    = bx >> 7;
  const int h    = (bx >> 3) & 15;
  const int iblk = bx & 7;
  const int jq   = t >> 6;         // wave id = j-quarter
  const int r    = t & 63;         // lane = row within block
  const int i    = iblk * 64 + r;
  const size_t qbase = (size_t)b * N_ * (3 * HID_);

  for (int idx = t; idx < N_ * 8; idx += 256) {
    const int j = idx >> 3, f = idx & 7;
    const float4 kv = *(const float4*)(qkv + qbase + (size_t)j * (3 * HID_) +
                                       HID_ + h * HD_ + f * 4);
    short4v ks;
    ks[0] = (short)f2bf(kv.x); ks[1] = (short)f2bf(kv.y);
    ks[2] = (short)f2bf(kv.z); ks[3] = (short)f2bf(kv.w);
    *(short4v*)&sm.k[j * HD_ + f * 4] = ks;
  }
  __syncthreads();

  float q[HD_];
  {
    const float* qp = qkv + qbase + (size_t)i * (3 * HID_) + h * HD_;
    #pragma unroll
    for (int f = 0; f < 8; ++f) {
      const float4 v = *(const float4*)(qp + f * 4);
      q[f*4+0] = v.x * 0.17677669529663687f;
      q[f*4+1] = v.y * 0.17677669529663687f;
      q[f*4+2] = v.z * 0.17677669529663687f;
      q[f*4+3] = v.w * 0.17677669529663687f;
    }
  }
  const u16* brow = biasb + (((size_t)b * HEADS_ + h) * N_ + i) * N_ + jq * 128;
  const float* vbase = qkv + qbase + 2 * HID_ + h * HD_;
  float m = -3.0e38f, l = 0.f;
  float o[HD_];
  #pragma unroll
  for (int d = 0; d < HD_; ++d) o[d] = 0.f;

  for (int jc = 0; jc < 128; jc += 16) {
    // ---- phase 1: 16 independent dot products ----
    float s[16];
    const short8v bq0 = *(const short8v*)(brow + jc);
    const short8v bq1 = *(const short8v*)(brow + jc + 8);
    #pragma unroll
    for (int e = 0; e < 16; ++e) {
      const int j = jq * 128 + jc + e;
      const u16* kr = &sm.k[j * HD_];
      float s0 = 0.f, s1 = 0.f, s2 = 0.f, s3 = 0.f;
      #pragma unroll
      for (int c = 0; c < 4; ++c) {
        const short8v kk = *(const short8v*)(kr + c * 8);
        s0 += q[c*8+0] * bf2f((u16)kk[0]);
        s1 += q[c*8+1] * bf2f((u16)kk[1]);
        s2 += q[c*8+2] * bf2f((u16)kk[2]);
        s3 += q[c*8+3] * bf2f((u16)kk[3]);
        s0 += q[c*8+4] * bf2f((u16)kk[4]);
        s1 += q[c*8+5] * bf2f((u16)kk[5]);
        s2 += q[c*8+6] * bf2f((u16)kk[6]);
        s3 += q[c*8+7] * bf2f((u16)kk[7]);
      }
      const float bb = bf2f((u16)(e < 8 ? bq0[e] : bq1[e - 8]));
      s[e] = (s0 + s1) + (s2 + s3) + bb;
    }
    // ---- phase 2: chunk max, one defer-max branch per chunk ----
    float mc = s[0];
    #pragma unroll
    for (int e = 1; e < 16; ++e) mc = fmaxf(mc, s[e]);
    if (mc - m > 8.0f) {                 // defer-max (T13), per-chunk
      const float corr = __expf(m - mc);
      l *= corr;
      #pragma unroll
      for (int d = 0; d < HD_; ++d) o[d] *= corr;
      m = mc;
    }
    // ---- phase 3: 16 independent exp, tree-sum into l ----
    #pragma unroll
    for (int e = 0; e < 16; ++e) s[e] = __expf(s[e] - m);
    {
      float t0 = (s[0]+s[1])+(s[2]+s[3]),  t1 = (s[4]+s[5])+(s[6]+s[7]);
      float t2 = (s[8]+s[9])+(s[10]+s[11]), t3 = (s[12]+s[13])+(s[14]+s[15]);
      l += (t0 + t1) + (t2 + t3);
    }
    // ---- phase 4: PV, all p ready -> loads pipeline freely ----
    #pragma unroll
    for (int e = 0; e < 16; ++e) {
      const int j = jq * 128 + jc + e;
      const float p = s[e];
      const float4* vr = (const float4*)(vbase + (size_t)j * (3 * HID_));
      #pragma unroll
      for (int c = 0; c < 8; ++c) {
        const float4 vv = vr[c];
        o[c*4+0] += p * vv.x; o[c*4+1] += p * vv.y;
        o[c*4+2] += p * vv.z; o[c*4+3] += p * vv.w;
      }
    }
  }

  __syncthreads();                  // Ks dead; LDS reused for combine
  if (jq > 0) {
    sm.c.pm[jq-1][r] = m;
    sm.c.pl[jq-1][r] = l;
    #pragma unroll
    for (int d = 0; d < HD_; ++d) sm.c.po[jq-1][r][d] = o[d];
  }
  __syncthreads();
  if (jq == 0) {
    #pragma unroll
    for (int p2 = 0; p2 < 3; ++p2) {
      const float m2 = sm.c.pm[p2][r], l2 = sm.c.pl[p2][r];
      const float mn = fmaxf(m, m2);
      const float c1 = __expf(m - mn), c2 = __expf(m2 - mn);
      l = l * c1 + l2 * c2;
      #pragma unroll
      for (int d = 0; d < HD_; ++d)
        o[d] = o[d] * c1 + sm.c.po[p2][r][d] * c2;
      m = mn;
    }
    const float inv = 1.0f / l;
    u16* cp = ctx + (((size_t)b * N_ + i) * HEADS_ + h) * HD_;
    #pragma unroll
    for (int f = 0; f < 4; ++f) {
      short8v v;
      #pragma unroll
      for (int e = 0; e < 8; ++e) v[e] = (short)f2bf(o[f*8+e] * inv);
      *(short8v*)(cp + f * 8) = v;
    }
  }
}

// ---------------- launcher ----------------
extern "C" void kernel_launch(void* const* d_in, const int* in_sizes, int n_in,
                              void* d_out, int out_size, void* d_ws, size_t ws_size,
                              hipStream_t stream) {
  const float* x      = (const float*)d_in[0];
  const float* df     = (const float*)d_in[1];
  const unsigned char* mask = (const unsigned char*)d_in[2];
  const float* qkv_w  = (const float*)d_in[3];
  const float* qkv_b  = (const float*)d_in[4];
  const float* out_w  = (const float*)d_in[5];
  const float* out_b  = (const float*)d_in[6];
  const float* dist_w = (const float*)d_in[7];
  const float* dist_b = (const float*)d_in[8];
  const float* ln1_g  = (const float*)d_in[9];
  const float* ln1_b  = (const float*)d_in[10];
  const float* ln2_g  = (const float*)d_in[11];
  const float* ln2_b  = (const float*)d_in[12];
  const float* ff1_w  = (const float*)d_in[13];
  const float* ff1_b  = (const float*)d_in[14];
  const float* ff2_w  = (const float*)d_in[15];
  const float* ff2_b  = (const float*)d_in[16];
  float* out = (float*)d_out;

  char* p = (char*)d_ws;
  auto alloc = [&](size_t bytes) {
    char* r = p;
    p += (bytes + 255) & ~(size_t)255;
    return r;
  };
  float* qkv    = (float*)alloc((size_t)ROWS * 3 * HID_ * 4);
  u16*   biasb  = (u16*)alloc((size_t)B_ * HEADS_ * N_ * N_ * 2);
  float* xa     = (float*)alloc((size_t)ROWS * HID_ * 4);
  u16*   h16    = (u16*)alloc((size_t)ROWS * HID_ * 2);
  u16*   ctx16  = (u16*)alloc((size_t)ROWS * HID_ * 2);
  u16*   y16    = (u16*)alloc((size_t)ROWS * HID_ * 2);
  u16*   ff116  = (u16*)alloc((size_t)ROWS * FFN_ * 2);
  u16*   qkv_wt = (u16*)alloc((size_t)3 * HID_ * HID_ * 2);
  u16*   out_wt = (u16*)alloc((size_t)HID_ * HID_ * 2);
  u16*   ff1_wt = (u16*)alloc((size_t)FFN_ * HID_ * 2);
  u16*   ff2_wt = (u16*)alloc((size_t)HID_ * FFN_ * 2);
  int*   flag   = (int*)alloc(sizeof(int));

  hipMemsetAsync(flag, 0, sizeof(int), stream);
  prep_kernel<<<3328, 256, 0, stream>>>(qkv_w, out_w, ff1_w, ff2_w,
                                        qkv_wt, out_wt, ff1_wt, ff2_wt,
                                        mask, flag);
  // h16 = bf16(LN1(x))
  ln_kernel<<<ROWS / 4, 256, 0, stream>>>(x, ln1_g, ln1_b, h16);
  // qkv = h @ qkv_w + qkv_b   (f32 out)
  mfma_gemm<0, false, false><<<dim3(3 * HID_ / 128, ROWS / 128), 256, 0, stream>>>(
      h16, qkv_wt, qkv_b, nullptr, qkv, 3 * HID_, HID_);
  // biasb = bf16 masked distance bias [B,H,N,N]  (MFMA)
  bias_kernel<<<B_ * N_ * 4, 256, 0, stream>>>(df, mask, dist_w, dist_b, flag, biasb);
  // ctx16 = bf16(softmax(QK^T/sqrt(hd) + biasb) @ V)
  attn_kernel<<<B_ * HEADS_ * 8, 256, 0, stream>>>(qkv, biasb, ctx16);
  // xa = x + ctx @ out_w + out_b   (f32 out)
  mfma_gemm<0, true, false><<<dim3(HID_ / 128, ROWS / 128), 256, 0, stream>>>(
      ctx16, out_wt, out_b, x, xa, HID_, HID_);
  // y16 = bf16(LN2(xa))
  ln_kernel<<<ROWS / 4, 256, 0, stream>>>(xa, ln2_g, ln2_b, y16);
  // ff116 = bf16(gelu(y @ ff1_w + ff1_b))
  mfma_gemm<1, false, true><<<dim3(FFN_ / 128, ROWS / 128), 256, 0, stream>>>(
      y16, ff1_wt, ff1_b, nullptr, ff116, FFN_, HID_);
  // out = xa + ff1 @ ff2_w + ff2_b   (f32 out)
  mfma_gemm<0, true, false><<<dim3(HID_ / 128, ROWS / 128), 256, 0, stream>>>(
      ff116, ff2_wt, ff2_b, xa, out, HID_, FFN_);
}

// Round 10
// 431.743 us; speedup vs baseline: 1.9190x; 1.0093x over previous
//
#include <hip/hip_runtime.h>
#include <cstddef>
#include <cstdint>

#define B_     8
#define N_     512
#define HID_   512
#define HEADS_ 16
#define HD_    32
#define FFN_   2048
#define DEMB_  64
#define ROWS   (B_*N_)   // 4096

typedef unsigned short u16;
typedef short bf16x8 __attribute__((ext_vector_type(8)));
typedef float f32x4  __attribute__((ext_vector_type(4)));
typedef short short8v __attribute__((ext_vector_type(8)));
typedef short short4v __attribute__((ext_vector_type(4)));

__device__ __forceinline__ u16 f2bf(float f) {   // RNE float->bf16
  unsigned u = __float_as_uint(f);
  u += 0x7fffu + ((u >> 16) & 1u);
  return (u16)(u >> 16);
}
__device__ __forceinline__ float bf2f(u16 b) {
  return __uint_as_float(((unsigned)b) << 16);
}

__device__ __forceinline__ void gload16(const void* g, void* l) {
  // async global->LDS, 16B/lane; LDS dest = wave-uniform base + lane*16
  __builtin_amdgcn_global_load_lds(
      (const __attribute__((address_space(1))) unsigned int*)g,
      (__attribute__((address_space(3))) unsigned int*)l, 16, 0, 0);
}

// ---------------- prep: 4x weight transpose-cast + mask dtype detect ----------------
__device__ __forceinline__ void wt_tile(const float* __restrict__ W,
                                        u16* __restrict__ Wt,
                                        int K, int N, int tt, int tid) {
  __shared__ float tile[32][33];
  const int nt = N / 32;
  const int n0 = (tt % nt) * 32, k0 = (tt / nt) * 32;
  const int tx = tid & 31, ty = tid >> 5;  // ty 0..7
  #pragma unroll
  for (int i = 0; i < 4; ++i)
    tile[ty + 8 * i][tx] = W[(size_t)(k0 + ty + 8 * i) * N + n0 + tx];
  __syncthreads();
  #pragma unroll
  for (int i = 0; i < 4; ++i) {
    const int n = ty + 8 * i;
    Wt[(size_t)(n0 + n) * K + k0 + tx] = f2bf(tile[tx][n]);
  }
}

__global__ __launch_bounds__(256) void prep_kernel(
    const float* __restrict__ qkv_w, const float* __restrict__ out_w,
    const float* __restrict__ ff1_w, const float* __restrict__ ff2_w,
    u16* __restrict__ qkv_wt, u16* __restrict__ out_wt,
    u16* __restrict__ ff1_wt, u16* __restrict__ ff2_wt,
    const unsigned char* __restrict__ mask, int* __restrict__ flag) {
  const int bid = blockIdx.x, t = threadIdx.x;
  if (bid < 768) {
    wt_tile(qkv_w, qkv_wt, HID_, 3 * HID_, bid, t);
  } else if (bid < 1024) {
    wt_tile(out_w, out_wt, HID_, HID_, bid - 768, t);
  } else if (bid < 2048) {
    wt_tile(ff1_w, ff1_wt, HID_, FFN_, bid - 1024, t);
  } else if (bid < 3072) {
    wt_tile(ff2_w, ff2_wt, FFN_, HID_, bid - 2048, t);
  } else {
    // mask dtype detect: numpy bool -> random bytes everywhere;
    // int32 0/1 -> bytes at offset%4 != 0 are always 0.
    const int idx = (bid - 3072) * 256 + t;   // 0..65535
    if ((idx & 3) != 0 && mask[idx] != 0) atomicOr(flag, 1);
  }
}

// ---------------- LayerNorm (fp32 in -> bf16 out): one wave per row ----------------
__global__ __launch_bounds__(256) void ln_kernel(const float* __restrict__ x,
                                                 const float* __restrict__ g,
                                                 const float* __restrict__ bt,
                                                 u16* __restrict__ y) {
  const int lane = threadIdx.x & 63;
  const int row  = blockIdx.x * 4 + (threadIdx.x >> 6);
  const float* xr = x + (size_t)row * HID_;
  float4 v0 = *(const float4*)(xr + lane * 8);
  float4 v1 = *(const float4*)(xr + lane * 8 + 4);
  float s = v0.x + v0.y + v0.z + v0.w + v1.x + v1.y + v1.z + v1.w;
  float q = v0.x*v0.x + v0.y*v0.y + v0.z*v0.z + v0.w*v0.w
          + v1.x*v1.x + v1.y*v1.y + v1.z*v1.z + v1.w*v1.w;
  #pragma unroll
  for (int off = 32; off > 0; off >>= 1) {
    s += __shfl_xor(s, off, 64);
    q += __shfl_xor(q, off, 64);
  }
  const float mean = s * (1.0f / HID_);
  const float var  = q * (1.0f / HID_) - mean * mean;
  const float rs   = rsqrtf(var + 1e-5f);
  const float4 g0 = *(const float4*)(g + lane * 8);
  const float4 g1 = *(const float4*)(g + lane * 8 + 4);
  const float4 b0 = *(const float4*)(bt + lane * 8);
  const float4 b1 = *(const float4*)(bt + lane * 8 + 4);
  short8v o;
  o[0] = (short)f2bf((v0.x - mean) * rs * g0.x + b0.x);
  o[1] = (short)f2bf((v0.y - mean) * rs * g0.y + b0.y);
  o[2] = (short)f2bf((v0.z - mean) * rs * g0.z + b0.z);
  o[3] = (short)f2bf((v0.w - mean) * rs * g0.w + b0.w);
  o[4] = (short)f2bf((v1.x - mean) * rs * g1.x + b1.x);
  o[5] = (short)f2bf((v1.y - mean) * rs * g1.y + b1.y);
  o[6] = (short)f2bf((v1.z - mean) * rs * g1.z + b1.z);
  o[7] = (short)f2bf((v1.w - mean) * rs * g1.w + b1.w);
  *(short8v*)(y + (size_t)row * HID_ + lane * 8) = o;
}

// ---------------- bf16 MFMA GEMM (single-buffer) ----------------
// A[M][K] bf16 row-major; Wt[N][K] bf16. 128x128 tile, BK=64, 4 waves,
// mfma_f32_16x16x32_bf16, fp32 accum. 32 KB LDS (dbuf regressed, m132-class).
// XOR swizzle (slot ^= row&7) on global source + ds_read (rule #21).
template <int ACT, bool HAS_RES, bool OUT_BF16>
__global__ __launch_bounds__(256) void mfma_gemm(
    const u16* __restrict__ A, const u16* __restrict__ Wt,
    const float* __restrict__ bias, const float* __restrict__ res,
    void* __restrict__ Cout, int N, int K) {
  __shared__ __align__(16) u16 As[128 * 64];
  __shared__ __align__(16) u16 Bs[128 * 64];
  const int t    = threadIdx.x;
  const int wid  = t >> 6, lane = t & 63;
  const int wr   = wid >> 1, wc = wid & 1;      // wave -> 64x64 quadrant
  const int m0   = blockIdx.y * 128, n0 = blockIdx.x * 128;
  const int srow8 = lane >> 3;                  // 0..7
  const int sslot = (lane & 7) ^ srow8;         // inverse-swizzled k-slot

  f32x4 zero = {0.f, 0.f, 0.f, 0.f};
  f32x4 acc[4][4];
  #pragma unroll
  for (int m = 0; m < 4; ++m)
    #pragma unroll
    for (int n = 0; n < 4; ++n) acc[m][n] = zero;

  for (int kt = 0; kt < K; kt += 64) {
    __syncthreads();   // previous compute done before overwriting LDS
    #pragma unroll
    for (int i = 0; i < 4; ++i) {
      const int rbase = wid * 32 + i * 8;
      const int r = rbase + srow8;
      gload16(A  + (size_t)(m0 + r) * K + kt + sslot * 8, &As[rbase * 64]);
      gload16(Wt + (size_t)(n0 + r) * K + kt + sslot * 8, &Bs[rbase * 64]);
    }
    __syncthreads();   // drains vmcnt(0) before barrier
    #pragma unroll
    for (int kk = 0; kk < 2; ++kk) {
      bf16x8 a[4], b[4];
      #pragma unroll
      for (int m = 0; m < 4; ++m) {
        const int row = wr * 64 + m * 16 + (lane & 15);
        const int s   = (kk * 4 + (lane >> 4)) ^ (row & 7);
        a[m] = *(const bf16x8*)&As[row * 64 + s * 8];
      }
      #pragma unroll
      for (int n = 0; n < 4; ++n) {
        const int row = wc * 64 + n * 16 + (lane & 15);
        const int s   = (kk * 4 + (lane >> 4)) ^ (row & 7);
        b[n] = *(const bf16x8*)&Bs[row * 64 + s * 8];
      }
      #pragma unroll
      for (int m = 0; m < 4; ++m)
        #pragma unroll
        for (int n = 0; n < 4; ++n)
          acc[m][n] = __builtin_amdgcn_mfma_f32_16x16x32_bf16(
              a[m], b[n], acc[m][n], 0, 0, 0);
    }
  }
  // epilogue: C/D layout col=lane&15, row=(lane>>4)*4+reg (m89-verified)
  #pragma unroll
  for (int n = 0; n < 4; ++n) {
    const int col = n0 + wc * 64 + n * 16 + (lane & 15);
    const float bb = bias[col];
    #pragma unroll
    for (int m = 0; m < 4; ++m) {
      #pragma unroll
      for (int j = 0; j < 4; ++j) {
        const int row = m0 + wr * 64 + m * 16 + (lane >> 4) * 4 + j;
        float v = acc[m][n][j] + bb;
        if (ACT == 1) v = 0.5f * v * (1.0f + erff(v * 0.70710678118654752f));
        const size_t off = (size_t)row * N + col;
        if (HAS_RES) v += res[off];
        if (OUT_BF16) ((u16*)Cout)[off] = f2bf(v);
        else          ((float*)Cout)[off] = v;
      }
    }
  }
}

// ---------------- fused distance-bias + mask (v4: MFMA) ----------------
__global__ __launch_bounds__(256) void bias_kernel(
    const float* __restrict__ df, const unsigned char* __restrict__ mask8,
    const float* __restrict__ dw, const float* __restrict__ db,
    const int* __restrict__ flag, u16* __restrict__ biasb) {
  __shared__ __align__(16) float dfs[128 * 64];   // 32 KB, group-swizzled
  __shared__ float wls[64 * 16];                  // 4 KB, [d][h] linear
  __shared__ float dbs[16];
  __shared__ unsigned char mbuf[128];
  __shared__ u16 obuf[16][132];                   // pad 132 -> conflict-free

  const int t    = threadIdx.x;
  const int wid  = t >> 6, lane = t & 63;
  const int tile = blockIdx.x & 3;
  const int i    = (blockIdx.x >> 2) & 511;
  const int b    = blockIdx.x >> 11;
  const int j0   = tile * 128;

  // stage df[128 rows][64 f32]: physical 16B-slot p of row r holds group p^(r&15)
  const size_t dfbase = (((size_t)b * N_ + i) * N_ + j0) * DEMB_;
  #pragma unroll
  for (int s = 0; s < 8; ++s) {
    const int r0 = wid * 32 + s * 4;
    const int r  = r0 + (lane >> 4);
    const int g  = (lane & 15) ^ (r & 15);
    gload16(df + dfbase + (size_t)r * DEMB_ + g * 4, &dfs[r0 * 64]);
  }
  // stage dist_w (f32 [64][16], 4KB, linear) + db + decoded mask
  *(float4*)&wls[t * 4] = ((const float4*)dw)[t];
  if (t < 16) dbs[t] = db[t];
  const int fb = *flag;
  if (t < 128) {
    const size_t midx = ((size_t)b * N_ + i) * N_ + j0 + t;
    mbuf[t] = fb ? (mask8[midx] != 0) : (((const int*)mask8)[midx] != 0);
  }
  __syncthreads();

  // B frags: lane holds col h=lane&15, k = kk*32 + (lane>>4)*8 + e
  bf16x8 bw[2];
  #pragma unroll
  for (int kk = 0; kk < 2; ++kk)
    #pragma unroll
    for (int e = 0; e < 8; ++e) {
      const int k = kk * 32 + (lane >> 4) * 8 + e;
      bw[kk][e] = (short)f2bf(wls[k * 16 + (lane & 15)]);
    }

  // A frags + MFMA: wave -> rows [wid*32, wid*32+32) as 2 tiles of 16
  f32x4 acc[2] = {{0.f,0.f,0.f,0.f},{0.f,0.f,0.f,0.f}};
  #pragma unroll
  for (int t8 = 0; t8 < 2; ++t8) {
    const int row = wid * 32 + t8 * 16 + (lane & 15);
    #pragma unroll
    for (int kk = 0; kk < 2; ++kk) {
      bf16x8 a;
      #pragma unroll
      for (int gg = 0; gg < 2; ++gg) {
        const int G = kk * 8 + (lane >> 4) * 2 + gg;
        const int p = G ^ (row & 15);
        const float4 v = *(const float4*)&dfs[row * 64 + p * 4];
        a[gg*4+0] = (short)f2bf(v.x); a[gg*4+1] = (short)f2bf(v.y);
        a[gg*4+2] = (short)f2bf(v.z); a[gg*4+3] = (short)f2bf(v.w);
      }
      acc[t8] = __builtin_amdgcn_mfma_f32_16x16x32_bf16(a, bw[kk], acc[t8], 0, 0, 0);
    }
  }

  // epilogue: C col=lane&15 (h), row=(lane>>4)*4+j -> obuf, then coalesced out
  const int h = lane & 15;
  #pragma unroll
  for (int t8 = 0; t8 < 2; ++t8)
    #pragma unroll
    for (int j = 0; j < 4; ++j) {
      const int jl = wid * 32 + t8 * 16 + (lane >> 4) * 4 + j;
      const float v = acc[t8][j] + dbs[h];
      obuf[h][jl] = f2bf(mbuf[jl] ? v : -1e30f);
    }
  __syncthreads();
  const int h2 = t >> 4, c = t & 15;
  u16* ob = biasb + (((size_t)b * HEADS_ + h2) * N_ + i) * N_ + j0;
  *(short8v*)(ob + c * 8) = *(const short8v*)&obuf[h2][c * 8];
}

// ---------------- flash attention v5: occupancy-fixed chunked loop ----------------
// grid = (b, h, iblk of 64 rows) = 1024 blocks; 256 thr = 4 waves.
// v5: __launch_bounds__(256,4) caps VGPR at 128 -> 4 blocks/CU -> all 1024
// blocks resident in ONE dispatch round (was ~145 VGPR -> 3/CU -> 2 rounds).
// Chunk shrunk 16->8 so live state (~82 + in-flight ~32) fits 128 spill-free.
__global__ __launch_bounds__(256, 4) void attn_kernel(
    const float* __restrict__ qkv, const u16* __restrict__ biasb,
    u16* __restrict__ ctx) {
  __shared__ union {
    u16 k[N_ * HD_];               // 32 KB  Ks[j][d]
    struct {
      float po[3][64][33];         // +1 pad -> conflict-free combine
      float pm[3][64];
      float pl[3][64];
    } c;
  } sm;
  const int t    = threadIdx.x;
  const int bx   = blockIdx.x;
  const int b    = bx >> 7;
  const int h    = (bx >> 3) & 15;
  const int iblk = bx & 7;
  const int jq   = t >> 6;         // wave id = j-quarter
  const int r    = t & 63;         // lane = row within block
  const int i    = iblk * 64 + r;
  const size_t qbase = (size_t)b * N_ * (3 * HID_);

  for (int idx = t; idx < N_ * 8; idx += 256) {
    const int j = idx >> 3, f = idx & 7;
    const float4 kv = *(const float4*)(qkv + qbase + (size_t)j * (3 * HID_) +
                                       HID_ + h * HD_ + f * 4);
    short4v ks;
    ks[0] = (short)f2bf(kv.x); ks[1] = (short)f2bf(kv.y);
    ks[2] = (short)f2bf(kv.z); ks[3] = (short)f2bf(kv.w);
    *(short4v*)&sm.k[j * HD_ + f * 4] = ks;
  }
  __syncthreads();

  float q[HD_];
  {
    const float* qp = qkv + qbase + (size_t)i * (3 * HID_) + h * HD_;
    #pragma unroll
    for (int f = 0; f < 8; ++f) {
      const float4 v = *(const float4*)(qp + f * 4);
      q[f*4+0] = v.x * 0.17677669529663687f;
      q[f*4+1] = v.y * 0.17677669529663687f;
      q[f*4+2] = v.z * 0.17677669529663687f;
      q[f*4+3] = v.w * 0.17677669529663687f;
    }
  }
  const u16* brow = biasb + (((size_t)b * HEADS_ + h) * N_ + i) * N_ + jq * 128;
  const float* vbase = qkv + qbase + 2 * HID_ + h * HD_;
  float m = -3.0e38f, l = 0.f;
  float o[HD_];
  #pragma unroll
  for (int d = 0; d < HD_; ++d) o[d] = 0.f;

  for (int jc = 0; jc < 128; jc += 8) {
    // ---- phase 1: 8 independent dot products ----
    float s[8];
    const short8v bq = *(const short8v*)(brow + jc);
    #pragma unroll
    for (int e = 0; e < 8; ++e) {
      const int j = jq * 128 + jc + e;
      const u16* kr = &sm.k[j * HD_];
      float s0 = 0.f, s1 = 0.f, s2 = 0.f, s3 = 0.f;
      #pragma unroll
      for (int c = 0; c < 4; ++c) {
        const short8v kk = *(const short8v*)(kr + c * 8);
        s0 += q[c*8+0] * bf2f((u16)kk[0]);
        s1 += q[c*8+1] * bf2f((u16)kk[1]);
        s2 += q[c*8+2] * bf2f((u16)kk[2]);
        s3 += q[c*8+3] * bf2f((u16)kk[3]);
        s0 += q[c*8+4] * bf2f((u16)kk[4]);
        s1 += q[c*8+5] * bf2f((u16)kk[5]);
        s2 += q[c*8+6] * bf2f((u16)kk[6]);
        s3 += q[c*8+7] * bf2f((u16)kk[7]);
      }
      s[e] = (s0 + s1) + (s2 + s3) + bf2f((u16)bq[e]);
    }
    // ---- phase 2: chunk max, one defer-max branch per chunk ----
    float mc = fmaxf(fmaxf(fmaxf(s[0], s[1]), fmaxf(s[2], s[3])),
                     fmaxf(fmaxf(s[4], s[5]), fmaxf(s[6], s[7])));
    if (mc - m > 8.0f) {                 // defer-max (T13), per-chunk
      const float corr = __expf(m - mc);
      l *= corr;
      #pragma unroll
      for (int d = 0; d < HD_; ++d) o[d] *= corr;
      m = mc;
    }
    // ---- phase 3: 8 independent exp, tree-sum into l ----
    #pragma unroll
    for (int e = 0; e < 8; ++e) s[e] = __expf(s[e] - m);
    l += ((s[0]+s[1])+(s[2]+s[3])) + ((s[4]+s[5])+(s[6]+s[7]));
    // ---- phase 4: PV, all p ready -> loads pipeline freely ----
    #pragma unroll
    for (int e = 0; e < 8; ++e) {
      const int j = jq * 128 + jc + e;
      const float p = s[e];
      const float4* vr = (const float4*)(vbase + (size_t)j * (3 * HID_));
      #pragma unroll
      for (int c = 0; c < 8; ++c) {
        const float4 vv = vr[c];
        o[c*4+0] += p * vv.x; o[c*4+1] += p * vv.y;
        o[c*4+2] += p * vv.z; o[c*4+3] += p * vv.w;
      }
    }
  }

  __syncthreads();                  // Ks dead; LDS reused for combine
  if (jq > 0) {
    sm.c.pm[jq-1][r] = m;
    sm.c.pl[jq-1][r] = l;
    #pragma unroll
    for (int d = 0; d < HD_; ++d) sm.c.po[jq-1][r][d] = o[d];
  }
  __syncthreads();
  if (jq == 0) {
    #pragma unroll
    for (int p2 = 0; p2 < 3; ++p2) {
      const float m2 = sm.c.pm[p2][r], l2 = sm.c.pl[p2][r];
      const float mn = fmaxf(m, m2);
      const float c1 = __expf(m - mn), c2 = __expf(m2 - mn);
      l = l * c1 + l2 * c2;
      #pragma unroll
      for (int d = 0; d < HD_; ++d)
        o[d] = o[d] * c1 + sm.c.po[p2][r][d] * c2;
      m = mn;
    }
    const float inv = 1.0f / l;
    u16* cp = ctx + (((size_t)b * N_ + i) * HEADS_ + h) * HD_;
    #pragma unroll
    for (int f = 0; f < 4; ++f) {
      short8v v;
      #pragma unroll
      for (int e = 0; e < 8; ++e) v[e] = (short)f2bf(o[f*8+e] * inv);
      *(short8v*)(cp + f * 8) = v;
    }
  }
}

// ---------------- launcher ----------------
extern "C" void kernel_launch(void* const* d_in, const int* in_sizes, int n_in,
                              void* d_out, int out_size, void* d_ws, size_t ws_size,
                              hipStream_t stream) {
  const float* x      = (const float*)d_in[0];
  const float* df     = (const float*)d_in[1];
  const unsigned char* mask = (const unsigned char*)d_in[2];
  const float* qkv_w  = (const float*)d_in[3];
  const float* qkv_b  = (const float*)d_in[4];
  const float* out_w  = (const float*)d_in[5];
  const float* out_b  = (const float*)d_in[6];
  const float* dist_w = (const float*)d_in[7];
  const float* dist_b = (const float*)d_in[8];
  const float* ln1_g  = (const float*)d_in[9];
  const float* ln1_b  = (const float*)d_in[10];
  const float* ln2_g  = (const float*)d_in[11];
  const float* ln2_b  = (const float*)d_in[12];
  const float* ff1_w  = (const float*)d_in[13];
  const float* ff1_b  = (const float*)d_in[14];
  const float* ff2_w  = (const float*)d_in[15];
  const float* ff2_b  = (const float*)d_in[16];
  float* out = (float*)d_out;

  char* p = (char*)d_ws;
  auto alloc = [&](size_t bytes) {
    char* r = p;
    p += (bytes + 255) & ~(size_t)255;
    return r;
  };
  float* qkv    = (float*)alloc((size_t)ROWS * 3 * HID_ * 4);
  u16*   biasb  = (u16*)alloc((size_t)B_ * HEADS_ * N_ * N_ * 2);
  float* xa     = (float*)alloc((size_t)ROWS * HID_ * 4);
  u16*   h16    = (u16*)alloc((size_t)ROWS * HID_ * 2);
  u16*   ctx16  = (u16*)alloc((size_t)ROWS * HID_ * 2);
  u16*   y16    = (u16*)alloc((size_t)ROWS * HID_ * 2);
  u16*   ff116  = (u16*)alloc((size_t)ROWS * FFN_ * 2);
  u16*   qkv_wt = (u16*)alloc((size_t)3 * HID_ * HID_ * 2);
  u16*   out_wt = (u16*)alloc((size_t)HID_ * HID_ * 2);
  u16*   ff1_wt = (u16*)alloc((size_t)FFN_ * HID_ * 2);
  u16*   ff2_wt = (u16*)alloc((size_t)HID_ * FFN_ * 2);
  int*   flag   = (int*)alloc(sizeof(int));

  hipMemsetAsync(flag, 0, sizeof(int), stream);
  prep_kernel<<<3328, 256, 0, stream>>>(qkv_w, out_w, ff1_w, ff2_w,
                                        qkv_wt, out_wt, ff1_wt, ff2_wt,
                                        mask, flag);
  // h16 = bf16(LN1(x))
  ln_kernel<<<ROWS / 4, 256, 0, stream>>>(x, ln1_g, ln1_b, h16);
  // qkv = h @ qkv_w + qkv_b   (f32 out)
  mfma_gemm<0, false, false><<<dim3(3 * HID_ / 128, ROWS / 128), 256, 0, stream>>>(
      h16, qkv_wt, qkv_b, nullptr, qkv, 3 * HID_, HID_);
  // biasb = bf16 masked distance bias [B,H,N,N]  (MFMA)
  bias_kernel<<<B_ * N_ * 4, 256, 0, stream>>>(df, mask, dist_w, dist_b, flag, biasb);
  // ctx16 = bf16(softmax(QK^T/sqrt(hd) + biasb) @ V)
  attn_kernel<<<B_ * HEADS_ * 8, 256, 0, stream>>>(qkv, biasb, ctx16);
  // xa = x + ctx @ out_w + out_b   (f32 out)
  mfma_gemm<0, true, false><<<dim3(HID_ / 128, ROWS / 128), 256, 0, stream>>>(
      ctx16, out_wt, out_b, x, xa, HID_, HID_);
  // y16 = bf16(LN2(xa))
  ln_kernel<<<ROWS / 4, 256, 0, stream>>>(xa, ln2_g, ln2_b, y16);
  // ff116 = bf16(gelu(y @ ff1_w + ff1_b))
  mfma_gemm<1, false, true><<<dim3(FFN_ / 128, ROWS / 128), 256, 0, stream>>>(
      y16, ff1_wt, ff1_b, nullptr, ff116, FFN_, HID_);
  // out = xa + ff1 @ ff2_w + ff2_b   (f32 out)
  mfma_gemm<0, true, false><<<dim3(HID_ / 128, ROWS / 128), 256, 0, stream>>>(
      ff116, ff2_wt, ff2_b, xa, out, HID_, FFN_);
}